// Round 7
// baseline (162.207 us; speedup 1.0000x reference)
//
#include <hip/hip_runtime.h>
#include <hip/hip_bf16.h>
#include <math.h>

#define Nn 4096
#define Hdim 256
#define Edim 128
#define Cdim 32
#define Vdim 64
#define Kdim 20
#define G4H 1024
#define OUTS 513

#define NB 8               // XCD buckets for lstm tiles
#define LMAX 160
#define MAXG (NB * LMAX)   // 1280 lstm slots
#define MAXT2 192          // loss tile slots

// pack segments (weights only now)
#define SEG_A 983040       // lstm W: 80u * 6st * 256r * 8p
#define SEG_D 81920        // Wlp:    32m * 4st * 80r * 8p
#define SEG_E 20480        // bsum
#define SEG_F 2560         // bl2
#define PACK_T (SEG_A + SEG_D + SEG_E + SEG_F)   // 1,088,000 = 4250*256

typedef short bf16x8 __attribute__((ext_vector_type(8)));
typedef float f32x4 __attribute__((ext_vector_type(4)));

__device__ __forceinline__ float sigmoidf_(float x) { return 1.0f / (1.0f + expf(-x)); }

__device__ __forceinline__ bf16x8 cvt8(float4 f0, float4 f1) {
    bf16x8 r;
    __hip_bfloat16 h;
    h = __float2bfloat16(f0.x); r[0] = *(short*)&h;
    h = __float2bfloat16(f0.y); r[1] = *(short*)&h;
    h = __float2bfloat16(f0.z); r[2] = *(short*)&h;
    h = __float2bfloat16(f0.w); r[3] = *(short*)&h;
    h = __float2bfloat16(f1.x); r[4] = *(short*)&h;
    h = __float2bfloat16(f1.y); r[5] = *(short*)&h;
    h = __float2bfloat16(f1.z); r[6] = *(short*)&h;
    h = __float2bfloat16(f1.w); r[7] = *(short*)&h;
    return r;
}

__device__ __forceinline__ void gl_lds16(const short* g, void* l) {
    __builtin_amdgcn_global_load_lds((const __attribute__((address_space(1))) void*)g,
                                     (__attribute__((address_space(3))) void*)l, 16, 0, 0);
}

// ---------------- k_prep: block 0 = bucketing; blocks 1.. = weight pack ----------------
// slot swizzle within each 64-elem (128B) LDS row: phys slot p holds logical chunk c = p ^ (r & 7)
__global__ __launch_bounds__(256) void k_prep(
    const int* __restrict__ cell_id, const int* __restrict__ category,
    const float* __restrict__ Wlin, const float* __restrict__ blin,
    const float* __restrict__ Wec, const float* __restrict__ bec,
    const float* __restrict__ Wrel, const float* __restrict__ brel,
    const float* __restrict__ W_ih, const float* __restrict__ b_ih,
    const float* __restrict__ W_hh, const float* __restrict__ b_hh,
    int* __restrict__ pperm, int* __restrict__ pperm2,
    int* __restrict__ tlist, int* __restrict__ tlist2, int* __restrict__ meta,
    short* __restrict__ Wp, short* __restrict__ Wlp,
    float* __restrict__ bsum, float* __restrict__ bl2)
{
    int t = threadIdx.x;
    if (blockIdx.x == 0) {
        // ---- bucketing ----
        __shared__ int cnt[Kdim], cur[Kdim], po[Kdim], tk[Kdim];
        __shared__ int cnt2[Cdim], cur2[Cdim], po2[Cdim], tk2[Cdim];
        if (t < Kdim) cnt[t] = 0;
        if (t < Cdim) cnt2[t] = 0;
        __syncthreads();
        for (int i = t; i < Nn; i += 256) {
            atomicAdd(&cnt[cell_id[i]], 1);
            atomicAdd(&cnt2[category[i]], 1);
        }
        __syncthreads();
        if (t == 0) {
            int acc = 0;
            for (int k = 0; k < Kdim; k++) { po[k] = acc; cur[k] = acc; tk[k] = (cnt[k] + 31) >> 5; acc += tk[k] * 32; }
            meta[0] = acc;
            acc = 0;
            for (int m = 0; m < Cdim; m++) { po2[m] = acc; cur2[m] = acc; tk2[m] = (cnt2[m] + 31) >> 5; acc += tk2[m] * 32; }
            meta[1] = acc;
        }
        __syncthreads();
        for (int i = t; i < Nn; i += 256) {
            int p = atomicAdd(&cur[cell_id[i]], 1);
            pperm[p] = i;
            int p2 = atomicAdd(&cur2[category[i]], 1);
            pperm2[p2] = i;
        }
        for (int i = t; i < MAXG; i += 256) tlist[3 * i] = -1;
        if (t < MAXT2) tlist2[3 * t] = -1;
        __syncthreads();
        for (int i = t; i < (Kdim + Cdim) * 32; i += 256) {
            if (i < Kdim * 32) {
                int k = i >> 5, j = i & 31;
                int s = cnt[k] + j;
                if (cnt[k] > 0 && s < tk[k] * 32) pperm[po[k] + s] = pperm[po[k]];
            } else {
                int ii = i - Kdim * 32;
                int m = ii >> 5, j = ii & 31;
                int s = cnt2[m] + j;
                if (cnt2[m] > 0 && s < tk2[m] * 32) pperm2[po2[m] + s] = pperm2[po2[m]];
            }
        }
        if (t < Kdim * 4) {
            int u = t, k = u >> 2, hb = u & 3, b = u & 7;
            int base = 0;
            for (int v = b; v < u; v += NB) base += tk[v >> 2];
            int n = tk[k], c = cnt[k];
            for (int s = 0; s < n; s++) {
                int slot = (base + s) * NB + b;
                if (slot < MAXG) {
                    int rc = min(32, c - s * 32);
                    tlist[3 * slot + 0] = k;
                    tlist[3 * slot + 1] = (po[k] >> 5) + s;
                    tlist[3 * slot + 2] = (hb * 64) | (rc << 16);
                }
            }
        }
        if (t >= 128 && t < 128 + Cdim) {
            int m = t - 128;
            int base = 0;
            for (int mm = 0; mm < m; mm++) base += tk2[mm];
            int n = tk2[m], c = cnt2[m];
            for (int s = 0; s < n; s++) {
                int slot = base + s;
                if (slot < MAXT2) {
                    int rc = min(32, c - s * 32);
                    tlist2[3 * slot + 0] = m;
                    tlist2[3 * slot + 1] = (po2[m] >> 5) + s;
                    tlist2[3 * slot + 2] = rc;
                }
            }
        }
        return;
    }

    // ---- weight pack ----
    int tid = (blockIdx.x - 1) * 256 + t;
    if (tid < SEG_A) {
        int u = tid / 12288;
        int rem = tid % 12288;
        int st = rem / 2048;
        int rem2 = rem % 2048;
        int r = rem2 >> 3, p = rem2 & 7;
        int k = u >> 2, hb = u & 3;
        int c = p ^ (r & 7);
        int kk = st * 64 + c * 8;
        int grow = (r >> 6) * Hdim + hb * 64 + (r & 63);
        const float* src = (kk < Edim) ? W_ih + ((size_t)k * G4H + grow) * Edim + kk
                                       : W_hh + ((size_t)k * G4H + grow) * Hdim + (kk - Edim);
        float4 f0 = *(const float4*)(src);
        float4 f1 = *(const float4*)(src + 4);
        *(bf16x8*)(Wp + ((size_t)(u * 6 + st) * 256 + r) * 64 + p * 8) = cvt8(f0, f1);
    } else if (tid < SEG_A + SEG_D) {
        int t4 = tid - SEG_A;
        int m = t4 / 2560;
        int rem = t4 % 2560;
        int st = rem / 640;
        int rem2 = rem % 640;
        int r = rem2 >> 3, q = rem2 & 7;
        int c = q ^ (r & 7);
        int kk = st * 64 + c * 8;
        float4 f0 = {0.f, 0.f, 0.f, 0.f}, f1 = {0.f, 0.f, 0.f, 0.f};
        if (r < 64) {
            const float* src = Wlin + ((size_t)m * Vdim + r) * Hdim + kk;
            f0 = *(const float4*)(src); f1 = *(const float4*)(src + 4);
        } else if (r < 66) {
            const float* src = Wec + (size_t)(r - 64) * Hdim + kk;
            f0 = *(const float4*)(src); f1 = *(const float4*)(src + 4);
        } else if (r < 71) {
            const float* src = Wrel + (size_t)(r - 66) * Hdim + kk;
            f0 = *(const float4*)(src); f1 = *(const float4*)(src + 4);
        }
        *(bf16x8*)(Wlp + (size_t)m * 20480 + st * 5120 + r * 64 + q * 8) = cvt8(f0, f1);
    } else if (tid < SEG_A + SEG_D + SEG_E) {
        int t5 = tid - SEG_A - SEG_D;
        int k = t5 >> 10, rem = t5 & 1023;
        bsum[t5] = b_ih[(size_t)k * G4H + rem] + b_hh[(size_t)k * G4H + rem];
    } else if (tid < PACK_T) {
        int t6 = tid - SEG_A - SEG_D - SEG_E;
        int m = t6 / 80, v = t6 % 80;
        float b = 0.f;
        if (v < 64) b = blin[m * Vdim + v];
        else if (v < 66) b = bec[v - 64];
        else if (v < 71) b = brel[v - 66];
        bl2[t6] = b;
    }
}

// ---------------- fused main: lstm tiles [0,MAXG), loss tiles [MAXG, MAXG+MAXT2) ----------------
// W from packed bf16 via async DMA; activations staged in-register from fp32 (cvt + swizzled ds_write)
__global__ __launch_bounds__(256, 4) void k_main(
    const float* __restrict__ inp, const float* __restrict__ h_prev,
    const float* __restrict__ c_prev, const float* __restrict__ vec,
    const short* __restrict__ Wp, const short* __restrict__ Wlp,
    const float* __restrict__ bsum, const float* __restrict__ bl2,
    const int* __restrict__ pperm, const int* __restrict__ pperm2,
    const int* __restrict__ tlist, const int* __restrict__ tlist2,
    const int* __restrict__ true_idx, const int* __restrict__ ec_idx, const int* __restrict__ rel_idx,
    float* __restrict__ out)
{
    __shared__ __align__(16) char smem[36992];
    int t = threadIdx.x;
    int w = t >> 6, l = t & 63;
    int l15 = l & 15, quad = l >> 4;

    if (blockIdx.x < MAXG) {
        // ============ LSTM tile: 32 rows x (64 h x 4 gates), K=384 ============
        int k = tlist[3 * blockIdx.x];
        if (k < 0) return;
        int pb = tlist[3 * blockIdx.x + 1];
        int e2 = tlist[3 * blockIdx.x + 2];
        int hb0 = e2 & 0xFFFF, rcount = e2 >> 16;
        int u = k * 4 + (hb0 >> 6);

        short* Wbuf = (short*)smem;             // 256 rows x 64 bf16 (32 KB)
        short* Xbuf = (short*)(smem + 32768);   // 32 rows x 64 bf16 (4 KB)
        int* rows_s = (int*)(smem + 36864);     // 32 ints

        if (t < 32) rows_s[t] = pperm[pb * 32 + t];

        const short* Wg = Wp + (size_t)u * 6 * 16384;

        // staging geometry: lane covers row rs = w*8 + (l>>3), phys slot q = l&7
        int rs = w * 8 + (l >> 3);
        int q = l & 7;
        int cc = q ^ (rs & 7);          // logical chunk held at phys slot q

        f32x4 acc[2][4];
        #pragma unroll
        for (int m = 0; m < 2; m++)
            #pragma unroll
            for (int g = 0; g < 4; g++)
                acc[m][g] = (f32x4){0.f, 0.f, 0.f, 0.f};

        for (int st = 0; st < 6; st++) {
            __syncthreads();
            // W tile via async DMA (pre-swizzled layout)
            #pragma unroll
            for (int j = 0; j < 8; j++)
                gl_lds16(Wg + st * 16384 + (w * 64 + j * 8) * 64 + l * 8,
                         smem + (w * 64 + j * 8) * 128);
            // X tile in-register: fp32 -> bf16 -> swizzled ds_write_b128
            {
                int kk = st * 64 + cc * 8;
                int row = rows_s[rs];
                const float* src = (kk < Edim) ? inp + (size_t)row * Edim + kk
                                               : h_prev + (size_t)row * Hdim + (kk - Edim);
                float4 f0 = *(const float4*)(src);
                float4 f1 = *(const float4*)(src + 4);
                *(bf16x8*)(smem + 32768 + rs * 128 + q * 16) = cvt8(f0, f1);
            }
            __syncthreads();
            #pragma unroll
            for (int ks = 0; ks < 2; ks++) {
                int p = (ks * 4 + quad) ^ (l15 & 7);
                bf16x8 af[2], bfr[4];
                #pragma unroll
                for (int m = 0; m < 2; m++)
                    af[m] = *(bf16x8*)((char*)Xbuf + (m * 16 + l15) * 128 + p * 16);
                #pragma unroll
                for (int g = 0; g < 4; g++)
                    bfr[g] = *(bf16x8*)((char*)Wbuf + (g * 64 + w * 16 + l15) * 128 + p * 16);
                #pragma unroll
                for (int m = 0; m < 2; m++)
                    #pragma unroll
                    for (int g = 0; g < 4; g++)
                        acc[m][g] = __builtin_amdgcn_mfma_f32_16x16x32_bf16(af[m], bfr[g], acc[m][g], 0, 0, 0);
            }
        }

        int h = hb0 + w * 16 + l15;
        float bs[4];
        #pragma unroll
        for (int g = 0; g < 4; g++)
            bs[g] = bsum[(size_t)k * G4H + g * Hdim + h];

        #pragma unroll
        for (int m = 0; m < 2; m++) {
            #pragma unroll
            for (int reg = 0; reg < 4; reg++) {
                int r = m * 16 + quad * 4 + reg;
                if (r < rcount) {
                    int row = rows_s[r];
                    float iv = acc[m][0][reg] + bs[0];
                    float fv = acc[m][1][reg] + bs[1];
                    float gv = acc[m][2][reg] + bs[2];
                    float ov = acc[m][3][reg] + bs[3];
                    float cp = c_prev[(size_t)row * Hdim + h];
                    float cn = sigmoidf_(fv) * cp + sigmoidf_(iv) * tanhf(gv);
                    float hn = sigmoidf_(ov) * tanhf(cn);
                    out[(size_t)row * OUTS + 1 + h] = hn;
                    out[(size_t)row * OUTS + 1 + Hdim + h] = cn;
                }
            }
        }
    } else {
        // ============ loss tile: 32 rows x 80 logits, K=256 ============
        int slot = blockIdx.x - MAXG;
        int cm = tlist2[3 * slot];
        if (cm < 0) return;
        int pb2 = tlist2[3 * slot + 1];
        int rcount = tlist2[3 * slot + 2];

        short* Wlbuf = (short*)smem;              // 80 x 64 bf16 (10240 B)
        short* Vbuf  = (short*)(smem + 10240);    // 32 x 64 bf16 (4096 B)
        float* Lg    = (float*)(smem + 14336);    // 32 x 84 fp32 (10752 B)
        int* rows2_s = (int*)(smem + 36864);      // 32 ints

        if (t < 32) rows2_s[t] = pperm2[pb2 * 32 + t];

        const short* Wg = Wlp + (size_t)cm * 20480;

        int rs = w * 8 + (l >> 3);
        int q = l & 7;
        int cc = q ^ (rs & 7);

        f32x4 a0[2], a1[2];
        #pragma unroll
        for (int m = 0; m < 2; m++) { a0[m] = (f32x4){0.f,0.f,0.f,0.f}; a1[m] = (f32x4){0.f,0.f,0.f,0.f}; }

        for (int st = 0; st < 4; st++) {
            __syncthreads();
            for (int n = w; n < 10; n += 4)
                gl_lds16(Wg + st * 5120 + n * 512 + l * 8, smem + n * 1024);
            {
                int kk = st * 64 + cc * 8;
                int row = rows2_s[rs];
                const float* src = vec + (size_t)row * Hdim + kk;
                float4 f0 = *(const float4*)(src);
                float4 f1 = *(const float4*)(src + 4);
                *(bf16x8*)(smem + 10240 + rs * 128 + q * 16) = cvt8(f0, f1);
            }
            __syncthreads();
            #pragma unroll
            for (int ks = 0; ks < 2; ks++) {
                int p = (ks * 4 + quad) ^ (l15 & 7);
                bf16x8 af[2];
                af[0] = *(bf16x8*)((char*)Vbuf + l15 * 128 + p * 16);
                af[1] = *(bf16x8*)((char*)Vbuf + (16 + l15) * 128 + p * 16);
                bf16x8 b0 = *(bf16x8*)((char*)Wlbuf + (w * 16 + l15) * 128 + p * 16);
                a0[0] = __builtin_amdgcn_mfma_f32_16x16x32_bf16(af[0], b0, a0[0], 0, 0, 0);
                a0[1] = __builtin_amdgcn_mfma_f32_16x16x32_bf16(af[1], b0, a0[1], 0, 0, 0);
                if (w == 3) {
                    bf16x8 b1 = *(bf16x8*)((char*)Wlbuf + (64 + l15) * 128 + p * 16);
                    a1[0] = __builtin_amdgcn_mfma_f32_16x16x32_bf16(af[0], b1, a1[0], 0, 0, 0);
                    a1[1] = __builtin_amdgcn_mfma_f32_16x16x32_bf16(af[1], b1, a1[1], 0, 0, 0);
                }
            }
        }
        __syncthreads();
        {
            int col = w * 16 + l15;
            float bb = bl2[cm * 80 + col];
            #pragma unroll
            for (int m = 0; m < 2; m++)
                #pragma unroll
                for (int reg = 0; reg < 4; reg++)
                    Lg[(m * 16 + quad * 4 + reg) * 84 + col] = a0[m][reg] + bb;
            if (w == 3) {
                int col1 = 64 + l15;
                float bb1 = bl2[cm * 80 + col1];
                #pragma unroll
                for (int m = 0; m < 2; m++)
                    #pragma unroll
                    for (int reg = 0; reg < 4; reg++)
                        Lg[(m * 16 + quad * 4 + reg) * 84 + col1] = a1[m][reg] + bb1;
            }
        }
        __syncthreads();
        for (int rr = 0; rr < 8; rr++) {
            int r = w * 8 + rr;
            if (r >= rcount) break;
            int orig = rows2_s[r];
            float lg = Lg[r * 84 + l];
            float mx = lg;
            for (int s = 32; s >= 1; s >>= 1) mx = fmaxf(mx, __shfl_xor(mx, s));
            float sm = expf(lg - mx);
            for (int s = 32; s >= 1; s >>= 1) sm += __shfl_xor(sm, s);
            float lt = __shfl(lg, true_idx[orig]);
            float loss = mx + logf(sm) - lt;
            if (l == 0) {
                float l0 = Lg[r * 84 + 64], l1 = Lg[r * 84 + 65];
                float me = fmaxf(l0, l1);
                loss += me + logf(expf(l0 - me) + expf(l1 - me)) - ((ec_idx[orig] == 0) ? l0 : l1);
                float rl[5] = { Lg[r * 84 + 66], Lg[r * 84 + 67], Lg[r * 84 + 68], Lg[r * 84 + 69], Lg[r * 84 + 70] };
                float mr = rl[0];
                #pragma unroll
                for (int i = 1; i < 5; i++) mr = fmaxf(mr, rl[i]);
                float sr = 0.f;
                #pragma unroll
                for (int i = 0; i < 5; i++) sr += expf(rl[i] - mr);
                loss += mr + logf(sr) - rl[rel_idx[orig]];
                out[(size_t)orig * OUTS] = loss;
            }
        }
    }
}

extern "C" void kernel_launch(void* const* d_in, const int* in_sizes, int n_in,
                              void* d_out, int out_size, void* d_ws, size_t ws_size,
                              hipStream_t stream) {
    const float* vec      = (const float*)d_in[0];
    const float* inp      = (const float*)d_in[1];
    const float* h_prev   = (const float*)d_in[2];
    const float* c_prev   = (const float*)d_in[3];
    const float* Wlin     = (const float*)d_in[4];
    const float* blin     = (const float*)d_in[5];
    const float* Wec      = (const float*)d_in[6];
    const float* bec      = (const float*)d_in[7];
    const float* Wrel     = (const float*)d_in[8];
    const float* brel     = (const float*)d_in[9];
    const float* W_ih     = (const float*)d_in[10];
    const float* b_ih     = (const float*)d_in[11];
    const float* W_hh     = (const float*)d_in[12];
    const float* b_hh     = (const float*)d_in[13];
    const int*   category = (const int*)d_in[14];
    const int*   cell_id  = (const int*)d_in[15];
    const int*   true_idx = (const int*)d_in[16];
    const int*   ec_idx   = (const int*)d_in[17];
    const int*   rel_idx  = (const int*)d_in[18];
    float* out = (float*)d_out;

    char* ws = (char*)d_ws;
    int*   pperm  = (int*)(ws);                    // 4736 ints
    int*   pperm2 = (int*)(ws + 18944);            // 5120 ints
    int*   tlist  = (int*)(ws + 39424);            // 3*1280 ints
    int*   tlist2 = (int*)(ws + 54784);            // 3*192 ints
    int*   meta   = (int*)(ws + 57088);            // 16 ints
    short* Wp     = (short*)(ws + 57344);          // 7,864,320 bf16
    short* Wlp    = (short*)(ws + 15785984);       // 655,360 bf16
    float* bsum   = (float*)(ws + 17096704);       // 20,480 fp32
    float* bl2    = (float*)(ws + 17178624);       // 2,560 fp32

    k_prep<<<1 + PACK_T / 256, 256, 0, stream>>>(
        cell_id, category, Wlin, blin, Wec, bec, Wrel, brel,
        W_ih, b_ih, W_hh, b_hh,
        pperm, pperm2, tlist, tlist2, meta, Wp, Wlp, bsum, bl2);

    k_main<<<MAXG + MAXT2, 256, 0, stream>>>(
        inp, h_prev, c_prev, vec, Wp, Wlp, bsum, bl2,
        pperm, pperm2, tlist, tlist2, true_idx, ec_idx, rel_idx, out);
}

// Round 8
// 156.899 us; speedup vs baseline: 1.0338x; 1.0338x over previous
//
#include <hip/hip_runtime.h>
#include <hip/hip_bf16.h>
#include <math.h>

#define Nn 4096
#define Hdim 256
#define Edim 128
#define Cdim 32
#define Vdim 64
#define Kdim 20
#define G4H 1024
#define OUTS 513

#define NB 8               // XCD buckets for lstm tiles
#define LMAX 160
#define MAXG (NB * LMAX)   // 1280 lstm slots
#define MAXT2 192          // loss tile slots
#define GRID (MAXG + MAXT2)

typedef short bf16x8 __attribute__((ext_vector_type(8)));
typedef float f32x4 __attribute__((ext_vector_type(4)));

__device__ __forceinline__ float sigmoidf_(float x) { return 1.0f / (1.0f + expf(-x)); }

__device__ __forceinline__ bf16x8 cvt8(float4 f0, float4 f1) {
    bf16x8 r;
    __hip_bfloat16 h;
    h = __float2bfloat16(f0.x); r[0] = *(short*)&h;
    h = __float2bfloat16(f0.y); r[1] = *(short*)&h;
    h = __float2bfloat16(f0.z); r[2] = *(short*)&h;
    h = __float2bfloat16(f0.w); r[3] = *(short*)&h;
    h = __float2bfloat16(f1.x); r[4] = *(short*)&h;
    h = __float2bfloat16(f1.y); r[5] = *(short*)&h;
    h = __float2bfloat16(f1.z); r[6] = *(short*)&h;
    h = __float2bfloat16(f1.w); r[7] = *(short*)&h;
    return r;
}

__device__ __forceinline__ void gl_lds16(const float* g, void* l) {
    __builtin_amdgcn_global_load_lds((const __attribute__((address_space(1))) void*)g,
                                     (__attribute__((address_space(3))) void*)l, 16, 0, 0);
}

// ================= single fused kernel =================
// blocks [0,MAXG): lstm tiles (32 rows x 64h x 4 gates, K=384)
// blocks [MAXG,GRID): loss tiles (32 rows x 80 logits, K=256)
// Each block re-derives the bucketing deterministically from cell_id/category.
__global__ __launch_bounds__(256, 4) void k_all(
    const float* __restrict__ vec, const float* __restrict__ inp,
    const float* __restrict__ h_prev, const float* __restrict__ c_prev,
    const float* __restrict__ Wlin, const float* __restrict__ blin,
    const float* __restrict__ Wec, const float* __restrict__ bec,
    const float* __restrict__ Wrel, const float* __restrict__ brel,
    const float* __restrict__ W_ih, const float* __restrict__ b_ih,
    const float* __restrict__ W_hh, const float* __restrict__ b_hh,
    const int* __restrict__ category, const int* __restrict__ cell_id,
    const int* __restrict__ true_idx, const int* __restrict__ ec_idx, const int* __restrict__ rel_idx,
    float* __restrict__ out)
{
    __shared__ __align__(16) char smem[37120];
    int* rows_s = (int*)(smem + 36864);          // persistent: 32 row indices
    int* cnt  = (int*)smem;                      // scratch (overwritten by GEMM staging)
    int* scan = (int*)(smem + 128);              // 256 ints
    int* map  = (int*)(smem + 1152);             // up to MAXG ints

    int t = threadIdx.x;
    bool is_lstm = blockIdx.x < MAXG;
    const int* key = is_lstm ? cell_id : category;
    int nbins = is_lstm ? Kdim : Cdim;
    int nslots = is_lstm ? MAXG : MAXT2;
    int myslot = is_lstm ? blockIdx.x : (blockIdx.x - MAXG);

    // ---- setup: histogram + slot map + deterministic rank-select ----
    if (t < nbins) cnt[t] = 0;
    for (int i = t; i < nslots; i += 256) map[i] = -1;
    __syncthreads();
    for (int i = t; i < Nn; i += 256) atomicAdd(&cnt[key[i]], 1);
    __syncthreads();
    if (is_lstm) {
        if (t < Kdim * 4) {
            int u = t, k = u >> 2, b = u & 7;
            int base = 0;
            for (int v = b; v < u; v += NB) base += (cnt[v >> 2] + 31) >> 5;
            int n = (cnt[k] + 31) >> 5;
            for (int s = 0; s < n; s++) {
                int slot = (base + s) * NB + b;
                if (slot < MAXG) map[slot] = u | (s << 8);
            }
        }
    } else {
        if (t < Cdim) {
            int m = t;
            int base = 0;
            for (int mm = 0; mm < m; mm++) base += (cnt[mm] + 31) >> 5;
            int n = (cnt[m] + 31) >> 5;
            for (int s = 0; s < n; s++) {
                int slot = base + s;
                if (slot < MAXT2) map[slot] = m | (s << 8);
            }
        }
    }
    __syncthreads();
    int me = map[myslot];
    if (me < 0) return;
    int myk = (me & 255);          // lstm: k*4+hb ; loss: m
    int s = me >> 8;
    int hb0 = 0;
    if (is_lstm) { hb0 = (myk & 3) * 64; myk >>= 2; }
    int w0 = s * 32;
    int rcount = min(32, cnt[myk] - w0);

    {   // deterministic rank-select of this tile's rows
        int i0 = t * 16;
        int local = 0;
        for (int i = i0; i < i0 + 16; i++) local += (key[i] == myk) ? 1 : 0;
        scan[t] = local;
        __syncthreads();
        for (int off = 1; off < 256; off <<= 1) {
            int v = scan[t];
            int add = (t >= off) ? scan[t - off] : 0;
            __syncthreads();
            scan[t] = v + add;
            __syncthreads();
        }
        int rank = scan[t] - local;   // exclusive prefix = #matches before i0
        for (int i = i0; i < i0 + 16; i++) {
            if (key[i] == myk) {
                if (rank >= w0 && rank < w0 + 32) rows_s[rank - w0] = i;
                rank++;
            }
        }
        __syncthreads();
        if (t < 32 && t >= rcount) rows_s[t] = rows_s[0];
        __syncthreads();
    }

    int w = t >> 6, l = t & 63;
    int l15 = l & 15, quad = l >> 4;
    int lrow8 = l >> 3, lslot = l & 7;
    int swz_l = ((l15 & 3) << 1) | ((l15 >> 2) & 1);
    int p0 = (quad * 2) ^ swz_l;

    if (is_lstm) {
        // ============ LSTM GEMM: fp32 direct DMA, 12 steps of BK=32 ============
        float* Wbuf = (float*)smem;            // 256 rows x 32 f32 (32 KB)
        float* Xbuf = (float*)(smem + 32768);  // 32 rows x 32 f32 (4 KB)
        const float* Wih_k = W_ih + (size_t)myk * G4H * Edim;
        const float* Whh_k = W_hh + (size_t)myk * G4H * Hdim;

        f32x4 acc[2][4];
        #pragma unroll
        for (int m = 0; m < 2; m++)
            #pragma unroll
            for (int g = 0; g < 4; g++)
                acc[m][g] = (f32x4){0.f, 0.f, 0.f, 0.f};

        int xr = w * 8 + lrow8;
        int xrow = rows_s[xr];
        int xg = lslot ^ (((xr & 3) << 1) | ((xr >> 2) & 1));

        for (int st = 0; st < 12; st++) {
            int k0 = st * 32;
            const float* Wsrc; int stride, ko;
            if (k0 < Edim) { Wsrc = Wih_k; stride = Edim; ko = k0; }
            else           { Wsrc = Whh_k; stride = Hdim; ko = k0 - Edim; }
            __syncthreads();
            #pragma unroll
            for (int j = 0; j < 8; j++) {
                int r = w * 64 + j * 8 + lrow8;
                int g = lslot ^ (((r & 3) << 1) | ((r >> 2) & 1));
                int gate = r >> 6, hl = r & 63;
                gl_lds16(Wsrc + (size_t)(gate * Hdim + hb0 + hl) * stride + ko + g * 4,
                         Wbuf + (w * 64 + j * 8) * 32);
            }
            gl_lds16((k0 < Edim ? inp + (size_t)xrow * Edim + ko
                                : h_prev + (size_t)xrow * Hdim + ko) + xg * 4,
                     Xbuf + (w * 8) * 32);
            __syncthreads();

            bf16x8 af[2], bfr[4];
            #pragma unroll
            for (int m = 0; m < 2; m++) {
                int row = m * 16 + l15;
                float4 lo = *(float4*)(Xbuf + row * 32 + p0 * 4);
                float4 hi = *(float4*)(Xbuf + row * 32 + (p0 ^ 1) * 4);
                af[m] = cvt8(lo, hi);
            }
            #pragma unroll
            for (int g = 0; g < 4; g++) {
                int row = g * 64 + w * 16 + l15;
                float4 lo = *(float4*)(Wbuf + row * 32 + p0 * 4);
                float4 hi = *(float4*)(Wbuf + row * 32 + (p0 ^ 1) * 4);
                bfr[g] = cvt8(lo, hi);
            }
            #pragma unroll
            for (int m = 0; m < 2; m++)
                #pragma unroll
                for (int g = 0; g < 4; g++)
                    acc[m][g] = __builtin_amdgcn_mfma_f32_16x16x32_bf16(af[m], bfr[g], acc[m][g], 0, 0, 0);
        }

        int h = hb0 + w * 16 + l15;
        float bs[4];
        #pragma unroll
        for (int g = 0; g < 4; g++)
            bs[g] = b_ih[(size_t)myk * G4H + g * Hdim + h] + b_hh[(size_t)myk * G4H + g * Hdim + h];

        #pragma unroll
        for (int m = 0; m < 2; m++) {
            #pragma unroll
            for (int reg = 0; reg < 4; reg++) {
                int r = m * 16 + quad * 4 + reg;
                if (r < rcount) {
                    int row = rows_s[r];
                    float iv = acc[m][0][reg] + bs[0];
                    float fv = acc[m][1][reg] + bs[1];
                    float gv = acc[m][2][reg] + bs[2];
                    float ov = acc[m][3][reg] + bs[3];
                    float cp = c_prev[(size_t)row * Hdim + h];
                    float cn = sigmoidf_(fv) * cp + sigmoidf_(iv) * tanhf(gv);
                    float hn = sigmoidf_(ov) * tanhf(cn);
                    out[(size_t)row * OUTS + 1 + h] = hn;
                    out[(size_t)row * OUTS + 1 + Hdim + h] = cn;
                }
            }
        }
    } else {
        // ============ loss GEMM: 32 rows x 80 logits, K=256, 8 steps of BK=32 ============
        float* Wlbuf = (float*)smem;              // 80 x 32 f32 (10240 B)
        float* Vbuf  = (float*)(smem + 10240);    // 32 x 32 f32 (4096 B)
        float* Lg    = (float*)(smem + 14336);    // 32 x 84 f32 (10752 B)
        int m2 = myk;

        f32x4 a0[2], a1[2];
        #pragma unroll
        for (int m = 0; m < 2; m++) { a0[m] = (f32x4){0.f,0.f,0.f,0.f}; a1[m] = (f32x4){0.f,0.f,0.f,0.f}; }

        int xr = w * 8 + lrow8;
        int xrow = rows_s[xr];
        int xg = lslot ^ (((xr & 3) << 1) | ((xr >> 2) & 1));

        for (int st = 0; st < 8; st++) {
            int ko = st * 32;
            __syncthreads();
            for (int n = w; n < 10; n += 4) {
                int r = n * 8 + lrow8;
                int g = lslot ^ (((r & 3) << 1) | ((r >> 2) & 1));
                const float* srcW;
                if (r < 64)      srcW = Wlin + ((size_t)m2 * Vdim + r) * Hdim;
                else if (r < 66) srcW = Wec + (size_t)(r - 64) * Hdim;
                else if (r < 71) srcW = Wrel + (size_t)(r - 66) * Hdim;
                else             srcW = Wlin + (size_t)m2 * Vdim * Hdim;   // dummy, cols 71..79 unused
                gl_lds16(srcW + ko + g * 4, Wlbuf + n * 8 * 32);
            }
            gl_lds16(vec + (size_t)xrow * Hdim + ko + xg * 4, Vbuf + (w * 8) * 32);
            __syncthreads();

            bf16x8 af[2];
            #pragma unroll
            for (int m = 0; m < 2; m++) {
                int row = m * 16 + l15;
                float4 lo = *(float4*)(Vbuf + row * 32 + p0 * 4);
                float4 hi = *(float4*)(Vbuf + row * 32 + (p0 ^ 1) * 4);
                af[m] = cvt8(lo, hi);
            }
            {
                int row = w * 16 + l15;
                float4 lo = *(float4*)(Wlbuf + row * 32 + p0 * 4);
                float4 hi = *(float4*)(Wlbuf + row * 32 + (p0 ^ 1) * 4);
                bf16x8 b0 = cvt8(lo, hi);
                a0[0] = __builtin_amdgcn_mfma_f32_16x16x32_bf16(af[0], b0, a0[0], 0, 0, 0);
                a0[1] = __builtin_amdgcn_mfma_f32_16x16x32_bf16(af[1], b0, a0[1], 0, 0, 0);
            }
            if (w == 3) {
                int row = 64 + l15;
                float4 lo = *(float4*)(Wlbuf + row * 32 + p0 * 4);
                float4 hi = *(float4*)(Wlbuf + row * 32 + (p0 ^ 1) * 4);
                bf16x8 b1 = cvt8(lo, hi);
                a1[0] = __builtin_amdgcn_mfma_f32_16x16x32_bf16(af[0], b1, a1[0], 0, 0, 0);
                a1[1] = __builtin_amdgcn_mfma_f32_16x16x32_bf16(af[1], b1, a1[1], 0, 0, 0);
            }
        }
        __syncthreads();
        {
            int col = w * 16 + l15;
            float bb = blin[m2 * Vdim + col];
            #pragma unroll
            for (int m = 0; m < 2; m++)
                #pragma unroll
                for (int reg = 0; reg < 4; reg++)
                    Lg[(m * 16 + quad * 4 + reg) * 84 + col] = a0[m][reg] + bb;
            if (w == 3) {
                int col1 = 64 + l15;
                float bb1 = (l15 < 2) ? bec[l15] : ((l15 < 7) ? brel[l15 - 2] : 0.f);
                #pragma unroll
                for (int m = 0; m < 2; m++)
                    #pragma unroll
                    for (int reg = 0; reg < 4; reg++)
                        Lg[(m * 16 + quad * 4 + reg) * 84 + col1] = a1[m][reg] + bb1;
            }
        }
        __syncthreads();
        for (int rr = 0; rr < 8; rr++) {
            int r = w * 8 + rr;
            if (r >= rcount) break;
            int orig = rows_s[r];
            float lg = Lg[r * 84 + l];
            float mx = lg;
            for (int ss = 32; ss >= 1; ss >>= 1) mx = fmaxf(mx, __shfl_xor(mx, ss));
            float sm = expf(lg - mx);
            for (int ss = 32; ss >= 1; ss >>= 1) sm += __shfl_xor(sm, ss);
            float lt = __shfl(lg, true_idx[orig]);
            float loss = mx + logf(sm) - lt;
            if (l == 0) {
                float l0 = Lg[r * 84 + 64], l1 = Lg[r * 84 + 65];
                float me2 = fmaxf(l0, l1);
                loss += me2 + logf(expf(l0 - me2) + expf(l1 - me2)) - ((ec_idx[orig] == 0) ? l0 : l1);
                float rl[5] = { Lg[r * 84 + 66], Lg[r * 84 + 67], Lg[r * 84 + 68], Lg[r * 84 + 69], Lg[r * 84 + 70] };
                float mr = rl[0];
                #pragma unroll
                for (int i = 1; i < 5; i++) mr = fmaxf(mr, rl[i]);
                float sr = 0.f;
                #pragma unroll
                for (int i = 0; i < 5; i++) sr += expf(rl[i] - mr);
                loss += mr + logf(sr) - rl[rel_idx[orig]];
                out[(size_t)orig * OUTS] = loss;
            }
        }
    }
}

extern "C" void kernel_launch(void* const* d_in, const int* in_sizes, int n_in,
                              void* d_out, int out_size, void* d_ws, size_t ws_size,
                              hipStream_t stream) {
    const float* vec      = (const float*)d_in[0];
    const float* inp      = (const float*)d_in[1];
    const float* h_prev   = (const float*)d_in[2];
    const float* c_prev   = (const float*)d_in[3];
    const float* Wlin     = (const float*)d_in[4];
    const float* blin     = (const float*)d_in[5];
    const float* Wec      = (const float*)d_in[6];
    const float* bec      = (const float*)d_in[7];
    const float* Wrel     = (const float*)d_in[8];
    const float* brel     = (const float*)d_in[9];
    const float* W_ih     = (const float*)d_in[10];
    const float* b_ih     = (const float*)d_in[11];
    const float* W_hh     = (const float*)d_in[12];
    const float* b_hh     = (const float*)d_in[13];
    const int*   category = (const int*)d_in[14];
    const int*   cell_id  = (const int*)d_in[15];
    const int*   true_idx = (const int*)d_in[16];
    const int*   ec_idx   = (const int*)d_in[17];
    const int*   rel_idx  = (const int*)d_in[18];
    float* out = (float*)d_out;

    k_all<<<GRID, 256, 0, stream>>>(
        vec, inp, h_prev, c_prev, Wlin, blin, Wec, bec, Wrel, brel,
        W_ih, b_ih, W_hh, b_hh, category, cell_id, true_idx, ec_idx, rel_idx, out);
}

// Round 9
// 153.386 us; speedup vs baseline: 1.0575x; 1.0229x over previous
//
#include <hip/hip_runtime.h>
#include <hip/hip_bf16.h>
#include <math.h>

#define Nn 4096
#define Hdim 256
#define Edim 128
#define Cdim 32
#define Vdim 64
#define Kdim 20
#define G4H 1024
#define OUTS 513

#define NB 8
#define LMAXL 96            // max lstm tiles per bucket (worst case 73)
#define MAXG (NB * LMAXL)   // 768 lstm slots
#define MAXT2 192           // loss slots (worst case 159)
#define GRID (MAXG + MAXT2)

typedef short bf16x8 __attribute__((ext_vector_type(8)));
typedef float f32x4 __attribute__((ext_vector_type(4)));

__device__ __forceinline__ float sigmoidf_(float x) { return 1.0f / (1.0f + expf(-x)); }

__device__ __forceinline__ bf16x8 cvt8(float4 f0, float4 f1) {
    bf16x8 r;
    __hip_bfloat16 h;
    h = __float2bfloat16(f0.x); r[0] = *(short*)&h;
    h = __float2bfloat16(f0.y); r[1] = *(short*)&h;
    h = __float2bfloat16(f0.z); r[2] = *(short*)&h;
    h = __float2bfloat16(f0.w); r[3] = *(short*)&h;
    h = __float2bfloat16(f1.x); r[4] = *(short*)&h;
    h = __float2bfloat16(f1.y); r[5] = *(short*)&h;
    h = __float2bfloat16(f1.z); r[6] = *(short*)&h;
    h = __float2bfloat16(f1.w); r[7] = *(short*)&h;
    return r;
}

__device__ __forceinline__ void gl_lds16(const float* g, void* l) {
    __builtin_amdgcn_global_load_lds((const __attribute__((address_space(1))) void*)g,
                                     (__attribute__((address_space(3))) void*)l, 16, 0, 0);
}

__device__ __forceinline__ int swz(int r) { return ((r & 3) << 1) | ((r >> 2) & 1); }

// ================= single fused kernel =================
__global__ __launch_bounds__(256, 4) void k_all(
    const float* __restrict__ vec, const float* __restrict__ inp,
    const float* __restrict__ h_prev, const float* __restrict__ c_prev,
    const float* __restrict__ Wlin, const float* __restrict__ blin,
    const float* __restrict__ Wec, const float* __restrict__ bec,
    const float* __restrict__ Wrel, const float* __restrict__ brel,
    const float* __restrict__ W_ih, const float* __restrict__ b_ih,
    const float* __restrict__ W_hh, const float* __restrict__ b_hh,
    const int* __restrict__ category, const int* __restrict__ cell_id,
    const int* __restrict__ true_idx, const int* __restrict__ ec_idx, const int* __restrict__ rel_idx,
    float* __restrict__ out)
{
    __shared__ __align__(16) char smem[40960];
    int* cntR = (int*)smem;                 // setup scratch: 32*16 replicas (2 KB)
    int* cntF = (int*)(smem + 8192);        // final counts (32 ints)
    int* wsum = (int*)(smem + 8320);        // 4 ints
    int* rows_tmp = (int*)(smem + 8448);    // 64 ints

    int t = threadIdx.x;
    int w = t >> 6, l = t & 63;
    int l15 = l & 15, quad = l >> 4;
    int lrow8 = l >> 3, lslot = l & 7;
    bool is_lstm = blockIdx.x < MAXG;
    const int* key = is_lstm ? cell_id : category;
    int nbins = is_lstm ? Kdim : Cdim;

    // ---- histogram (x16 replicated) ----
    for (int i = t; i < nbins * 16; i += 256) cntR[i] = 0;
    __syncthreads();
    int4 kv0 = ((const int4*)key)[t * 4 + 0];
    int4 kv1 = ((const int4*)key)[t * 4 + 1];
    int4 kv2 = ((const int4*)key)[t * 4 + 2];
    int4 kv3 = ((const int4*)key)[t * 4 + 3];
    int ks[16] = { kv0.x, kv0.y, kv0.z, kv0.w, kv1.x, kv1.y, kv1.z, kv1.w,
                   kv2.x, kv2.y, kv2.z, kv2.w, kv3.x, kv3.y, kv3.z, kv3.w };
    int rep = t & 15;
    #pragma unroll
    for (int j = 0; j < 16; j++) atomicAdd(&cntR[ks[j] * 16 + rep], 1);
    __syncthreads();
    if (t < nbins) {
        int s2 = 0;
        #pragma unroll
        for (int r2 = 0; r2 < 16; r2++) s2 += cntR[t * 16 + r2];
        cntF[t] = s2;
    }
    __syncthreads();

    // ---- direct slot decode (no map array) ----
    int myk, s_idx, hb0 = 0, rcount, wlen;
    if (is_lstm) {
        int b = blockIdx.x & 7, pos = blockIdx.x >> 3;
        int u = -1, sf = 0, acc = 0;
        for (int uu = b; uu < Kdim * 4; uu += NB) {
            int n = (cntF[uu >> 2] + 63) >> 6;
            if (u < 0 && pos < acc + n) { u = uu; sf = pos - acc; }
            acc += n;
        }
        if (u < 0) return;
        myk = u >> 2; hb0 = (u & 3) * 64; s_idx = sf;
        wlen = 64;
        rcount = min(64, cntF[myk] - s_idx * 64);
    } else {
        int slot = blockIdx.x - MAXG;
        int u = -1, sf = 0, acc = 0;
        for (int m = 0; m < Cdim; m++) {
            int n = (cntF[m] + 31) >> 5;
            if (u < 0 && slot < acc + n) { u = m; sf = slot - acc; }
            acc += n;
        }
        if (u < 0) return;
        myk = u; s_idx = sf;
        wlen = 32;
        rcount = min(32, cntF[myk] - s_idx * 32);
    }

    // ---- rank-select via wave shfl scan ----
    {
        int local = 0;
        #pragma unroll
        for (int j = 0; j < 16; j++) local += (ks[j] == myk) ? 1 : 0;
        int v = local;
        #pragma unroll
        for (int off = 1; off < 64; off <<= 1) {
            int n = __shfl_up(v, off);
            if (l >= off) v += n;
        }
        if (l == 63) wsum[w] = v;
        __syncthreads();
        int wbase = 0;
        #pragma unroll
        for (int ww = 0; ww < 4; ww++) wbase += (ww < w) ? wsum[ww] : 0;
        int rank = wbase + v - local;
        int w0 = s_idx * wlen;
        #pragma unroll
        for (int j = 0; j < 16; j++) {
            if (ks[j] == myk) {
                int rr = rank - w0;
                if (rr >= 0 && rr < wlen) rows_tmp[rr] = t * 16 + j;
                rank++;
            }
        }
        __syncthreads();
        if (t < wlen && t >= rcount) rows_tmp[t] = rows_tmp[0];
        __syncthreads();
    }
    int reg_row = rows_tmp[is_lstm ? l : (l & 31)];
    int swz_l = swz(l15);
    int p0 = (quad * 2) ^ swz_l;

    if (is_lstm) {
        // ============ LSTM: 64 rows x (64 h x 4 gates), K=384, fp32 DMA BK=32 ============
        float* Wbuf = (float*)smem;            // 256 x 32 f32 (32 KB)
        float* Xbuf = (float*)(smem + 32768);  // 64 x 32 f32 (8 KB)
        const float* Wih_k = W_ih + (size_t)myk * G4H * Edim;
        const float* Whh_k = W_hh + (size_t)myk * G4H * Hdim;

        int xr0 = w * 16 + lrow8;
        int xr1 = w * 16 + 8 + lrow8;
        int xrow0 = __shfl(reg_row, xr0);
        int xrow1 = __shfl(reg_row, xr1);
        int xg0 = lslot ^ swz(xr0);
        int xg1 = lslot ^ swz(xr1);

        f32x4 acc[4][4];
        #pragma unroll
        for (int m = 0; m < 4; m++)
            #pragma unroll
            for (int g = 0; g < 4; g++)
                acc[m][g] = (f32x4){0.f, 0.f, 0.f, 0.f};

        for (int st = 0; st < 12; st++) {
            int k0 = st * 32;
            const float* Wsrc; int stride, ko;
            if (k0 < Edim) { Wsrc = Wih_k; stride = Edim; ko = k0; }
            else           { Wsrc = Whh_k; stride = Hdim; ko = k0 - Edim; }
            const float* Xs0 = (k0 < Edim) ? inp + (size_t)xrow0 * Edim + ko
                                           : h_prev + (size_t)xrow0 * Hdim + (ko - 0);
            const float* Xs1 = (k0 < Edim) ? inp + (size_t)xrow1 * Edim + ko
                                           : h_prev + (size_t)xrow1 * Hdim + (ko - 0);
            __syncthreads();
            #pragma unroll
            for (int j = 0; j < 8; j++) {
                int r = w * 64 + j * 8 + lrow8;
                int g = lslot ^ swz(r);
                int gate = r >> 6, hl = r & 63;
                gl_lds16(Wsrc + (size_t)(gate * Hdim + hb0 + hl) * stride + ko + g * 4,
                         Wbuf + (w * 64 + j * 8) * 32);
            }
            gl_lds16(Xs0 + xg0 * 4, Xbuf + (w * 16) * 32);
            gl_lds16(Xs1 + xg1 * 4, Xbuf + (w * 16 + 8) * 32);
            __syncthreads();

            bf16x8 af[4], bfr[4];
            #pragma unroll
            for (int m = 0; m < 4; m++) {
                int row = m * 16 + l15;
                float4 lo = *(float4*)(Xbuf + row * 32 + p0 * 4);
                float4 hi = *(float4*)(Xbuf + row * 32 + (p0 ^ 1) * 4);
                af[m] = cvt8(lo, hi);
            }
            #pragma unroll
            for (int g = 0; g < 4; g++) {
                int row = g * 64 + w * 16 + l15;
                float4 lo = *(float4*)(Wbuf + row * 32 + p0 * 4);
                float4 hi = *(float4*)(Wbuf + row * 32 + (p0 ^ 1) * 4);
                bfr[g] = cvt8(lo, hi);
            }
            #pragma unroll
            for (int m = 0; m < 4; m++)
                #pragma unroll
                for (int g = 0; g < 4; g++)
                    acc[m][g] = __builtin_amdgcn_mfma_f32_16x16x32_bf16(af[m], bfr[g], acc[m][g], 0, 0, 0);
        }

        int h = hb0 + w * 16 + l15;
        float bs[4];
        #pragma unroll
        for (int g = 0; g < 4; g++)
            bs[g] = b_ih[(size_t)myk * G4H + g * Hdim + h] + b_hh[(size_t)myk * G4H + g * Hdim + h];

        #pragma unroll
        for (int m = 0; m < 4; m++) {
            #pragma unroll
            for (int reg = 0; reg < 4; reg++) {
                int r = m * 16 + quad * 4 + reg;
                int row = __shfl(reg_row, r);
                if (r < rcount) {
                    float iv = acc[m][0][reg] + bs[0];
                    float fv = acc[m][1][reg] + bs[1];
                    float gv = acc[m][2][reg] + bs[2];
                    float ov = acc[m][3][reg] + bs[3];
                    float cp = c_prev[(size_t)row * Hdim + h];
                    float cn = sigmoidf_(fv) * cp + sigmoidf_(iv) * tanhf(gv);
                    float hn = sigmoidf_(ov) * tanhf(cn);
                    out[(size_t)row * OUTS + 1 + h] = hn;
                    out[(size_t)row * OUTS + 1 + Hdim + h] = cn;
                }
            }
        }
    } else {
        // ============ loss: 32 rows x 80 logits, K=256, fp32 DMA BK=32 ============
        float* Wlbuf = (float*)smem;              // 80 x 32 f32 (10240 B)
        float* Vbuf  = (float*)(smem + 10240);    // 32 x 32 f32 (4096 B)
        float* Lg    = (float*)(smem + 14336);    // 32 x 84 f32 (10752 B)
        int m2 = myk;

        int xr = w * 8 + lrow8;
        int xrow = __shfl(reg_row, xr);
        int xg = lslot ^ swz(xr);

        f32x4 a0[2], a1[2];
        #pragma unroll
        for (int m = 0; m < 2; m++) { a0[m] = (f32x4){0.f,0.f,0.f,0.f}; a1[m] = (f32x4){0.f,0.f,0.f,0.f}; }

        for (int st = 0; st < 8; st++) {
            int ko = st * 32;
            __syncthreads();
            for (int n = w; n < 10; n += 4) {
                int r = n * 8 + lrow8;
                int g = lslot ^ swz(r);
                const float* srcW;
                if (r < 64)      srcW = Wlin + ((size_t)m2 * Vdim + r) * Hdim;
                else if (r < 66) srcW = Wec + (size_t)(r - 64) * Hdim;
                else if (r < 71) srcW = Wrel + (size_t)(r - 66) * Hdim;
                else             srcW = Wlin + (size_t)m2 * Vdim * Hdim;
                gl_lds16(srcW + ko + g * 4, Wlbuf + n * 8 * 32);
            }
            gl_lds16(vec + (size_t)xrow * Hdim + ko + xg * 4, Vbuf + (w * 8) * 32);
            __syncthreads();

            bf16x8 af[2];
            #pragma unroll
            for (int m = 0; m < 2; m++) {
                int row = m * 16 + l15;
                float4 lo = *(float4*)(Vbuf + row * 32 + p0 * 4);
                float4 hi = *(float4*)(Vbuf + row * 32 + (p0 ^ 1) * 4);
                af[m] = cvt8(lo, hi);
            }
            {
                int row = w * 16 + l15;
                float4 lo = *(float4*)(Wlbuf + row * 32 + p0 * 4);
                float4 hi = *(float4*)(Wlbuf + row * 32 + (p0 ^ 1) * 4);
                bf16x8 b0 = cvt8(lo, hi);
                a0[0] = __builtin_amdgcn_mfma_f32_16x16x32_bf16(af[0], b0, a0[0], 0, 0, 0);
                a0[1] = __builtin_amdgcn_mfma_f32_16x16x32_bf16(af[1], b0, a0[1], 0, 0, 0);
            }
            if (w == 3) {
                int row = 64 + l15;
                float4 lo = *(float4*)(Wlbuf + row * 32 + p0 * 4);
                float4 hi = *(float4*)(Wlbuf + row * 32 + (p0 ^ 1) * 4);
                bf16x8 b1 = cvt8(lo, hi);
                a1[0] = __builtin_amdgcn_mfma_f32_16x16x32_bf16(af[0], b1, a1[0], 0, 0, 0);
                a1[1] = __builtin_amdgcn_mfma_f32_16x16x32_bf16(af[1], b1, a1[1], 0, 0, 0);
            }
        }
        __syncthreads();
        {
            int col = w * 16 + l15;
            float bb = blin[m2 * Vdim + col];
            #pragma unroll
            for (int m = 0; m < 2; m++)
                #pragma unroll
                for (int reg = 0; reg < 4; reg++)
                    Lg[(m * 16 + quad * 4 + reg) * 84 + col] = a0[m][reg] + bb;
            if (w == 3) {
                int col1 = 64 + l15;
                float bb1 = (l15 < 2) ? bec[l15] : ((l15 < 7) ? brel[l15 - 2] : 0.f);
                #pragma unroll
                for (int m = 0; m < 2; m++)
                    #pragma unroll
                    for (int reg = 0; reg < 4; reg++)
                        Lg[(m * 16 + quad * 4 + reg) * 84 + col1] = a1[m][reg] + bb1;
            }
        }
        __syncthreads();
        for (int rr = 0; rr < 8; rr++) {
            int r = w * 8 + rr;
            if (r >= rcount) break;
            int orig = __shfl(reg_row, r);
            float lg = Lg[r * 84 + l];
            float mx = lg;
            for (int ss = 32; ss >= 1; ss >>= 1) mx = fmaxf(mx, __shfl_xor(mx, ss));
            float sm = expf(lg - mx);
            for (int ss = 32; ss >= 1; ss >>= 1) sm += __shfl_xor(sm, ss);
            float lt = __shfl(lg, true_idx[orig]);
            float loss = mx + logf(sm) - lt;
            if (l == 0) {
                float l0 = Lg[r * 84 + 64], l1 = Lg[r * 84 + 65];
                float me2 = fmaxf(l0, l1);
                loss += me2 + logf(expf(l0 - me2) + expf(l1 - me2)) - ((ec_idx[orig] == 0) ? l0 : l1);
                float rl[5] = { Lg[r * 84 + 66], Lg[r * 84 + 67], Lg[r * 84 + 68], Lg[r * 84 + 69], Lg[r * 84 + 70] };
                float mr = rl[0];
                #pragma unroll
                for (int i = 1; i < 5; i++) mr = fmaxf(mr, rl[i]);
                float sr = 0.f;
                #pragma unroll
                for (int i = 0; i < 5; i++) sr += expf(rl[i] - mr);
                loss += mr + logf(sr) - rl[rel_idx[orig]];
                out[(size_t)orig * OUTS] = loss;
            }
        }
    }
}

extern "C" void kernel_launch(void* const* d_in, const int* in_sizes, int n_in,
                              void* d_out, int out_size, void* d_ws, size_t ws_size,
                              hipStream_t stream) {
    const float* vec      = (const float*)d_in[0];
    const float* inp      = (const float*)d_in[1];
    const float* h_prev   = (const float*)d_in[2];
    const float* c_prev   = (const float*)d_in[3];
    const float* Wlin     = (const float*)d_in[4];
    const float* blin     = (const float*)d_in[5];
    const float* Wec      = (const float*)d_in[6];
    const float* bec      = (const float*)d_in[7];
    const float* Wrel     = (const float*)d_in[8];
    const float* brel     = (const float*)d_in[9];
    const float* W_ih     = (const float*)d_in[10];
    const float* b_ih     = (const float*)d_in[11];
    const float* W_hh     = (const float*)d_in[12];
    const float* b_hh     = (const float*)d_in[13];
    const int*   category = (const int*)d_in[14];
    const int*   cell_id  = (const int*)d_in[15];
    const int*   true_idx = (const int*)d_in[16];
    const int*   ec_idx   = (const int*)d_in[17];
    const int*   rel_idx  = (const int*)d_in[18];
    float* out = (float*)d_out;

    k_all<<<GRID, 256, 0, stream>>>(
        vec, inp, h_prev, c_prev, Wlin, blin, Wec, bec, Wrel, brel,
        W_ih, b_ih, W_hh, b_hh, category, cell_id, true_idx, ec_idx, rel_idx, out);
}